// Round 10
// baseline (14428.564 us; speedup 1.0000x reference)
//
#include <hip/hip_runtime.h>

// FeedbackTransformerKV — persistent kernel, round 10.
// r9 structure, ONE change: work assignment. r9 assumed bid%8 == XCD so the
// 16 blocks sharing a column-slice co-locate on one XCD (making their 2.6MB
// weight slice L2-resident). FETCH_SIZE (28.6MB/step = full weight set) says
// that assumption is FALSE: slices are scattered, per-XCD working set
// overflows 4MB L2, and every GEMV streams from MALL. Fix: each block reads
// its physical XCD via s_getreg(HW_REG_XCC_ID) and CLAIMS a (g, cs=XCD) slot
// via per-XCD counters (overflow blocks take leftover slots after all 128
// claimed). Locality by construction; any bijection is correct.

#define S_ 128
#define B_ 16
#define D_ 512
#define H_ 8
#define DK_ 64
#define DFF_ 2048
#define L_ 4
#define P_ 4096

#define NBLK 128
#define NTHR 1024

struct FtkvParams {
  const float *x_seq, *w_query, *qpb, *kpe, *w_out, *b_out;
  const float *ln1_g, *ln1_b, *ln2_g, *ln2_b;
  const float *w_ff1, *b_ff1, *w_ff2, *b_ff2;
  const float *norm_g, *norm_b, *comb_w, *w_key, *w_value;
  float *out;
  float *dpart;     // [16 g][8 cs][512]
  float *dpart2;    // [16 g][8 cs][512]
  unsigned *memK;   // [16 g][8 h][128 slot][32 dw]  bf16 pairs
  unsigned *memV;   // [16 g][8 h][128 slot][32 dw]
  const uint4 *wqp;  // [64 k8][512 col]  (uint4 = 8 bf16 along k)
  const uint4 *wop;  // per layer stride 64*512
  const uint4 *w1p;  // per layer [64 k8][2048]
  const uint4 *w2p;  // per layer [256 k8][512]
  const uint4 *wkp;  // [64 k8][512]
  const uint4 *wvp;  // [64 k8][512]
  unsigned int *bar;
};

__device__ __forceinline__ float cload(const float *p_) {
  return __hip_atomic_load(p_, __ATOMIC_RELAXED, __HIP_MEMORY_SCOPE_AGENT);
}
__device__ __forceinline__ void cstore(float *p_, float v) {
  __hip_atomic_store(p_, v, __ATOMIC_RELAXED, __HIP_MEMORY_SCOPE_AGENT);
}
__device__ __forceinline__ unsigned aload(const unsigned *p_) {
  return __hip_atomic_load(p_, __ATOMIC_RELAXED, __HIP_MEMORY_SCOPE_AGENT);
}

__device__ __forceinline__ float waveRedSum(float v) {
#pragma unroll
  for (int off = 32; off; off >>= 1) v += __shfl_xor(v, off, 64);
  return v;
}
__device__ __forceinline__ float waveRedMax(float v) {
#pragma unroll
  for (int off = 32; off; off >>= 1) v = fmaxf(v, __shfl_xor(v, off, 64));
  return v;
}

#define UNPK(w, flo, fhi)                                     \
  float flo = __uint_as_float((unsigned)(w) << 16);           \
  float fhi = __uint_as_float((unsigned)(w) & 0xffff0000u);

__device__ __forceinline__ float dot8(const float *z, uint4 w) {
  UNPK(w.x, a0, a1); UNPK(w.y, b0, b1);
  UNPK(w.z, c0, c1); UNPK(w.w, d0, d1);
  return ((z[0] * a0 + z[1] * a1) + (z[2] * b0 + z[3] * b1)) +
         ((z[4] * c0 + z[5] * c1) + (z[6] * d0 + z[7] * d1));
}

// Group barrier: RELAXED arrive; waiters poll the arrive counter directly.
__device__ __forceinline__ void gbarN(unsigned *arr, unsigned &epoch,
                                      unsigned n) {
  __syncthreads();
  const unsigned e = ++epoch;
  if (threadIdx.x == 0) {
    __hip_atomic_fetch_add(arr, 1u, __ATOMIC_RELAXED,
                           __HIP_MEMORY_SCOPE_AGENT);
    while (__hip_atomic_load(arr, __ATOMIC_RELAXED,
                             __HIP_MEMORY_SCOPE_AGENT) < e * n)
      __builtin_amdgcn_s_sleep(1);
  }
  __syncthreads();
}

__global__ void ftkv_init(unsigned *bar) {
  for (int i = threadIdx.x; i < 4096; i += 256) bar[i] = 0u;
}

__device__ __forceinline__ unsigned bf16rne(float x) {
  unsigned b = __float_as_uint(x);
  return (b + 0x7fffu + ((b >> 16) & 1u)) >> 16;
}

// src[K][N] fp32 -> dst dwords laid out as [K/8][N][4]
__global__ void ftkv_pack(const float *src, unsigned *dst, int K, int N) {
  int total = (K / 2) * N;
  int n4 = N * 4;
  for (int i = blockIdx.x * blockDim.x + threadIdx.x; i < total;
       i += gridDim.x * blockDim.x) {
    int k8 = i / n4, rem = i - k8 * n4;
    int col = rem >> 2, q = rem & 3;
    int r0 = 8 * k8 + 2 * q;
    dst[i] = bf16rne(src[(size_t)r0 * N + col]) |
             (bf16rne(src[(size_t)(r0 + 1) * N + col]) << 16);
  }
}

#define LNSTATS(val, mu_, rs_)                                             \
  {                                                                        \
    __syncthreads();                                                       \
    if (tid < 512) {                                                       \
      float _s1 = waveRedSum(val), _s2 = waveRedSum((val) * (val));        \
      if (lane == 0) { sRed[wid] = _s1; sRed[8 + wid] = _s2; }             \
    }                                                                      \
    __syncthreads();                                                       \
    if (tid == 0) {                                                        \
      float _a = 0.f, _c = 0.f;                                            \
      for (int _i = 0; _i < 8; ++_i) { _a += sRed[_i]; _c += sRed[8 + _i];}\
      float _mu = _a * (1.f / 512.f);                                      \
      float _var = _c * (1.f / 512.f) - _mu * _mu;                         \
      sRed[16] = _mu; sRed[17] = rsqrtf(_var + 1e-5f);                     \
    }                                                                      \
    __syncthreads();                                                       \
    mu_ = sRed[16]; rs_ = sRed[17];                                        \
  }

__global__ __launch_bounds__(NTHR, 4) void ftkv_main(FtkvParams p) {
  const int tid = threadIdx.x;
  const int lane = tid & 63, wid = tid >> 6;

  __shared__ float sZ[512];
  __shared__ float sP[1024];
  __shared__ float sH[256];
  __shared__ float sQ[64], sQB[64], sS[128], sRed[20];
  __shared__ int sAssign[2];

  // ---- claim a (g, cs) slot with cs == this block's physical XCD ----
  // counters: bar[2048 + x*32] per-XCD claim count; bar[2048+256] excess.
  if (tid == 0) {
    unsigned x;
    asm volatile("s_getreg_b32 %0, hwreg(HW_REG_XCC_ID)" : "=s"(x));
    x &= 7u;
    unsigned *cnt = p.bar + 2048;
    unsigned n = __hip_atomic_fetch_add(&cnt[x * 32], 1u, __ATOMIC_RELAXED,
                                        __HIP_MEMORY_SCOPE_AGENT);
    int mycs, myg;
    if (n < 16u) {
      mycs = (int)x;
      myg = (int)n;
    } else {
      // wait until all NBLK blocks have claimed, then take a leftover slot
      for (;;) {
        unsigned s = 0;
        for (int i = 0; i < 8; ++i) s += aload(&cnt[i * 32]);
        if (s >= (unsigned)NBLK) break;
        __builtin_amdgcn_s_sleep(8);
      }
      unsigned e = __hip_atomic_fetch_add(&cnt[256], 1u, __ATOMIC_RELAXED,
                                          __HIP_MEMORY_SCOPE_AGENT);
      mycs = 0; myg = 0;
      for (int c = 0; c < 8; ++c) {
        unsigned cc = aload(&cnt[c * 32]);
        unsigned used = cc < 16u ? cc : 16u;
        unsigned u = 16u - used;
        if (e < u) { mycs = c; myg = (int)(used + e); break; }
        e -= u;
      }
    }
    sAssign[0] = mycs;
    sAssign[1] = myg;
  }
  __syncthreads();
  const int cs = sAssign[0];  // col-slice == head == physical XCD
  const int g = sAssign[1];   // batch element (group)

  unsigned *garr = p.bar + g * 32;
  unsigned gep = 0;

  float cw0 = p.comb_w[0], cw1 = p.comb_w[1], cw2 = p.comb_w[2],
        cw3 = p.comb_w[3], cw4 = p.comb_w[4];
  float cm = fmaxf(fmaxf(fmaxf(cw0, cw1), fmaxf(cw2, cw3)), cw4);
  float e0 = __expf(cw0 - cm), e1 = __expf(cw1 - cm), e2 = __expf(cw2 - cm),
        e3 = __expf(cw3 - cm), e4 = __expf(cw4 - cm);
  float einv = 1.0f / (e0 + e1 + e2 + e3 + e4);
  float comb0 = e0 * einv, comb1 = e1 * einv, comb2 = e2 * einv,
        comb3 = e3 * einv, comb4 = e4 * einv;

  // full x and macc copies in lower 512 threads (tid == column)
  float xr = 0.f, mr = 0.f;
  if (tid < 512) {
    xr = p.x_seq[g * D_ + tid];
    mr = comb0 * xr;
  }

  unsigned *memKb = p.memK + ((size_t)(g * H_ + cs)) * S_ * 32;
  unsigned *memVb = p.memV + ((size_t)(g * H_ + cs)) * S_ * 32;

  for (int t = 0; t < S_; ++t) {
    for (int l = 0; l < L_; ++l) {
      // ---- entry update: apply FF(l-1) partials; macc += comb[l]*x ----
      if (l > 0 && tid < 512) {
        float s = p.b_ff2[(l - 1) * D_ + tid];
#pragma unroll
        for (int c2 = 0; c2 < 8; ++c2)
          s += cload(&p.dpart2[((size_t)g * 8 + c2) * D_ + tid]);
        xr += s;
        const float cl = (l == 1) ? comb1 : (l == 2) ? comb2 : comb3;
        mr += cl * xr;
      }

      // =================== Phase A: attention (t>0) =====================
      if (t > 0) {
        float mu, rs;
        LNSTATS(xr, mu, rs);
        if (tid < 512)
          sZ[tid] = (xr - mu) * rs * p.ln1_g[l * D_ + tid] +
                    p.ln1_b[l * D_ + tid];
        __syncthreads();
        // q projection: thread=(d=tid&63, ks=tid>>6 in 0..15), 4 uint4 each
        {
          int d = tid & 63, ks = tid >> 6;
          const uint4 *wq = p.wqp + (size_t)l * 64 * 512 + cs * 64 + d;
          float acc = 0.f;
#pragma unroll
          for (int j = 0; j < 4; ++j) {
            int k8 = ks * 4 + j;
            acc += dot8(&sZ[8 * k8], wq[(size_t)k8 * 512]);
          }
          sP[tid] = acc;
        }
        __syncthreads();
        if (tid < 64) {
          float q = 0.f;
#pragma unroll
          for (int ks = 0; ks < 16; ++ks) q += sP[ks * 64 + tid];
          sQ[tid] = q;
          sQB[tid] = q + p.qpb[(l * H_ + cs) * 64 + tid];
        }
        __syncthreads();
        // scores: thread=(j=tid&127, ds=tid>>7 in 0..7), 8 dims each
        {
          int j = tid & 127, ds = tid >> 7;
          float acc = 0.f;
          if (j < t) {
            uint4 mku = ((const uint4 *)(memKb + (size_t)j * 32))[ds];
            const float4 *kp = (const float4 *)(p.kpe +
                (((size_t)l * P_ + (P_ - t + j)) * H_ + cs) * 64 + ds * 8);
            float4 b0 = kp[0], b1 = kp[1];
            UNPK(mku.x, k0, k1); UNPK(mku.y, k2, k3);
            UNPK(mku.z, k4, k5); UNPK(mku.w, k6, k7);
            const float *qb = &sQB[ds * 8], *qr = &sQ[ds * 8];
            acc = (qb[0] * k0 + qb[1] * k1 + qb[2] * k2 + qb[3] * k3) +
                  (qb[4] * k4 + qb[5] * k5 + qb[6] * k6 + qb[7] * k7) +
                  (qr[0] * b0.x + qr[1] * b0.y + qr[2] * b0.z + qr[3] * b0.w) +
                  (qr[4] * b1.x + qr[5] * b1.y + qr[6] * b1.z + qr[7] * b1.w);
          }
          sP[tid] = acc;
        }
        __syncthreads();
        if (tid < 128) {
          float sc = ((sP[tid] + sP[tid + 128]) + (sP[tid + 256] + sP[tid + 384])) +
                     ((sP[tid + 512] + sP[tid + 640]) + (sP[tid + 768] + sP[tid + 896]));
          sS[tid] = (tid < t) ? sc * 0.125f : -1e30f;
        }
        __syncthreads();
        if (tid < 64) {
          float m = waveRedMax(fmaxf(sS[tid], sS[tid + 64]));
          if (tid == 0) sRed[18] = m;
        }
        __syncthreads();
        if (tid < 128)
          sS[tid] = (tid < t) ? __expf(sS[tid] - sRed[18]) : 0.f;
        __syncthreads();
        if (tid < 64) {
          float s = waveRedSum(sS[tid] + sS[tid + 64]);
          if (tid == 0) sRed[19] = s;
        }
        __syncthreads();
        // av: thread=(d=tid&63, js=tid>>6 in 0..15), 8 slots each
        {
          int d = tid & 63, js = tid >> 6;
          int j0 = js * 8, j1 = (j0 + 8 < t) ? (j0 + 8) : t;
          float acc = 0.f;
          const ushort *mv = (const ushort *)memVb;
          for (int j = j0; j < j1; ++j) {
            float vv = __uint_as_float(((unsigned)mv[(size_t)j * 64 + d]) << 16);
            acc += sS[j] * vv;
          }
          sP[tid] = acc;
        }
        __syncthreads();
        if (tid < 64) {
          float a = 0.f;
#pragma unroll
          for (int js = 0; js < 16; ++js) a += sP[js * 64 + tid];
          sQ[tid] = a / sRed[19];  // av (head cs)
        }
        __syncthreads();
        // Wout partial: thread=(col=tid&511, ks=tid>>9 in 0..1), 4 uint4
        {
          int col = tid & 511, ks = tid >> 9;
          const uint4 *wo = p.wop + (size_t)l * 64 * 512 + col;
          float acc = 0.f;
#pragma unroll
          for (int j = 0; j < 4; ++j) {
            int k8l = ks * 4 + j;
            acc += dot8(&sQ[8 * k8l], wo[(size_t)(cs * 8 + k8l) * 512]);
          }
          sP[tid] = acc;
        }
        __syncthreads();
        if (tid < 512)
          cstore(&p.dpart[((size_t)g * 8 + cs) * D_ + tid],
                 sP[tid] + sP[512 + tid]);
        gbarN(garr, gep, 8);
      }

      // =================== Phase B: out-proj apply + LN2 + FF ===========
      if (t > 0 && tid < 512) {
        float s = p.b_out[l * D_ + tid];
#pragma unroll
        for (int c2 = 0; c2 < 8; ++c2)
          s += cload(&p.dpart[((size_t)g * 8 + c2) * D_ + tid]);
        xr += s;
      }
      {
        float mu, rs;
        LNSTATS(xr, mu, rs);
        if (tid < 512)
          sZ[tid] = (xr - mu) * rs * p.ln2_g[l * D_ + tid] +
                    p.ln2_b[l * D_ + tid];
      }
      __syncthreads();
      // FF1: thread=(c=tid&255, ks=tid>>8 in 0..3), 16 uint4 each
      {
        int c = tid & 255, ks = tid >> 8;
        const uint4 *w1 = p.w1p + (size_t)l * 64 * DFF_ + cs * 256 + c;
        float acc = 0.f;
#pragma unroll 8
        for (int j = 0; j < 16; ++j) {
          int k8 = ks * 16 + j;
          acc += dot8(&sZ[8 * k8], w1[(size_t)k8 * DFF_]);
        }
        sP[tid] = acc;
      }
      __syncthreads();
      if (tid < 256) {
        float h = ((sP[tid] + sP[256 + tid]) + (sP[512 + tid] + sP[768 + tid])) +
                  p.b_ff1[l * DFF_ + cs * 256 + tid];
        sH[tid] = fmaxf(h, 0.f);
      }
      __syncthreads();
      // FF2 partial: thread=(col=tid&511, ks=tid>>9 in 0..1), 16 uint4
      {
        int col = tid & 511, ks = tid >> 9;
        const uint4 *w2 = p.w2p + (size_t)l * 256 * 512 + col;
        float acc = 0.f;
#pragma unroll 8
        for (int j = 0; j < 16; ++j) {
          int k8l = ks * 16 + j;
          acc += dot8(&sH[8 * k8l], w2[(size_t)(cs * 32 + k8l) * 512]);
        }
        sP[tid] = acc;
      }
      __syncthreads();
      if (tid < 512)
        cstore(&p.dpart2[((size_t)g * 8 + cs) * D_ + tid],
               sP[tid] + sP[512 + tid]);
      gbarN(garr, gep, 8);
    } // layers

    // ====== Phase E (group-local, no barrier): KV slot t; out; next x ====
    if (tid < 512) {
      float s = p.b_ff2[3 * D_ + tid];
#pragma unroll
      for (int c2 = 0; c2 < 8; ++c2)
        s += cload(&p.dpart2[((size_t)g * 8 + c2) * D_ + tid]);
      xr += s;
      mr += comb4 * xr;
      sZ[tid] = mr;
    }
    __syncthreads();
    // K/V proj: thread=(kv=tid>>9, r=tid&511 -> d=r&63, ks=r>>6), 8 uint4
    {
      int kv = tid >> 9, r = tid & 511, d = r & 63, ks = r >> 6;
      const uint4 *w4 = (kv ? p.wvp : p.wkp) + cs * 64 + d;
      float acc = 0.f;
#pragma unroll
      for (int j = 0; j < 8; ++j) {
        int k8 = ks * 8 + j;
        acc += dot8(&sZ[8 * k8], w4[(size_t)k8 * 512]);
      }
      sP[tid] = acc;
    }
    __syncthreads();
    if (tid < 128) {
      int kv = tid >> 6, d = tid & 63;
      float v = 0.f;
#pragma unroll
      for (int ks = 0; ks < 8; ++ks) v += sP[kv * 512 + ks * 64 + d];
      sS[tid] = v;  // stage fp32: [0..63]=K dims, [64..127]=V dims
    }
    __syncthreads();
    if (tid < 64) {
      int kv = tid >> 5, d2 = tid & 31;
      float lo = sS[kv * 64 + 2 * d2], hi = sS[kv * 64 + 2 * d2 + 1];
      unsigned pk = bf16rne(lo) | (bf16rne(hi) << 16);
      unsigned *dst = kv ? memVb : memKb;
      dst[(size_t)t * 32 + d2] = pk;
    }
    {
      float mu, rs;
      LNSTATS(xr, mu, rs);
      if (tid < 512 && (tid >> 6) == cs)
        p.out[((size_t)t * B_ + g) * D_ + tid] =
            (xr - mu) * rs * p.norm_g[tid] + p.norm_b[tid];
    }
    if (t + 1 < S_ && tid < 512) {
      xr = p.x_seq[((size_t)(t + 1) * B_ + g) * D_ + tid];
      mr = comb0 * xr;
    }
    // no barrier: E is group-local; next A-barrier orders everything
  } // t
}

extern "C" void kernel_launch(void *const *d_in, const int *in_sizes, int n_in,
                              void *d_out, int out_size, void *d_ws,
                              size_t ws_size, hipStream_t stream) {
  (void)in_sizes; (void)n_in; (void)out_size; (void)ws_size;

  FtkvParams p;
  p.x_seq  = (const float *)d_in[0];
  p.w_query = (const float *)d_in[1];
  p.qpb    = (const float *)d_in[2];
  p.kpe    = (const float *)d_in[3];
  p.w_out  = (const float *)d_in[4];
  p.b_out  = (const float *)d_in[5];
  p.ln1_g  = (const float *)d_in[6];
  p.ln1_b  = (const float *)d_in[7];
  p.ln2_g  = (const float *)d_in[8];
  p.ln2_b  = (const float *)d_in[9];
  p.w_ff1  = (const float *)d_in[10];
  p.b_ff1  = (const float *)d_in[11];
  p.w_ff2  = (const float *)d_in[12];
  p.b_ff2  = (const float *)d_in[13];
  p.norm_g = (const float *)d_in[14];
  p.norm_b = (const float *)d_in[15];
  p.comb_w = (const float *)d_in[16];
  p.w_key  = (const float *)d_in[17];
  p.w_value = (const float *)d_in[18];
  p.out = (float *)d_out;

  char *ws = (char *)d_ws;
  p.bar = (unsigned int *)ws; // 16KB
  float *f = (float *)(ws + 16384);
  p.dpart  = f; f += B_ * 8 * D_;
  p.dpart2 = f; f += B_ * 8 * D_;
  unsigned *u = (unsigned *)f;
  p.memK = u; u += B_ * H_ * S_ * 32;  // bf16-pair dwords
  p.memV = u; u += B_ * H_ * S_ * 32;
  unsigned *wqp = u; u += L_ * 256 * 512;
  unsigned *wop = u; u += L_ * 256 * 512;
  unsigned *w1p = u; u += L_ * 256 * DFF_;
  unsigned *w2p = u; u += L_ * 1024 * 512;
  unsigned *wkp = u; u += 256 * 512;
  unsigned *wvp = u; u += 256 * 512;
  p.wqp = (const uint4 *)wqp; p.wop = (const uint4 *)wop;
  p.w1p = (const uint4 *)w1p; p.w2p = (const uint4 *)w2p;
  p.wkp = (const uint4 *)wkp; p.wvp = (const uint4 *)wvp;

  ftkv_init<<<dim3(1), dim3(256), 0, stream>>>(p.bar);
  for (int l = 0; l < L_; ++l) {
    ftkv_pack<<<dim3(256), dim3(256), 0, stream>>>(
        p.w_query + (size_t)l * 512 * 512, wqp + (size_t)l * 256 * 512, 512, 512);
    ftkv_pack<<<dim3(256), dim3(256), 0, stream>>>(
        p.w_out + (size_t)l * 512 * 512, wop + (size_t)l * 256 * 512, 512, 512);
    ftkv_pack<<<dim3(512), dim3(256), 0, stream>>>(
        p.w_ff1 + (size_t)l * 512 * DFF_, w1p + (size_t)l * 256 * DFF_, 512, DFF_);
    ftkv_pack<<<dim3(512), dim3(256), 0, stream>>>(
        p.w_ff2 + (size_t)l * DFF_ * 512, w2p + (size_t)l * 1024 * 512, DFF_, 512);
  }
  ftkv_pack<<<dim3(256), dim3(256), 0, stream>>>(p.w_key, wkp, 512, 512);
  ftkv_pack<<<dim3(256), dim3(256), 0, stream>>>(p.w_value, wvp, 512, 512);
  ftkv_main<<<dim3(NBLK), dim3(NTHR), 0, stream>>>(p);
}